// Round 10
// baseline (80.996 us; speedup 1.0000x reference)
//
#include <hip/hip_runtime.h>
#include <cstdint>

constexpr int BTOT  = 1048576;
constexpr int LCLS  = 81;
constexpr int GRP   = 9;
constexpr int ROWS  = 32;                    // rows per block (one wave; lanes 0-31 compute)
constexpr int THR   = 64;
constexpr int NBLK  = BTOT / ROWS;           // 32768
constexpr int TILEF = ROWS * LCLS;           // 2592 floats = 10,368 B -> 15 blocks/CU
constexpr int TILE4 = TILEF / 4;             // 648 float4
constexpr int FULLR = TILE4 / THR;           // 10 full DMA rounds
constexpr int TAIL  = TILE4 - FULLR * THR;   // 8 leftover float4 (lanes < 8)
constexpr float FIX = 1048576.0f;            // 2^20 fixed-point loss scale (u32-safe)

// Async global->LDS, 16B per lane, no VGPR round-trip (m97 pattern).
__device__ __forceinline__ void gload_lds16(const float* gsrc, float* ldst) {
    __builtin_amdgcn_global_load_lds(
        (const __attribute__((address_space(1))) void*)gsrc,
        (__attribute__((address_space(3))) void*)ldst,
        16, 0, 0);
}

// Rare knife-edge path (~1e-5 of rows): group argmax in f64 from global row.
__device__ __attribute__((noinline)) int refine_group_f64(const float* __restrict__ xrow)
{
    double best = -1.0; int bi = 0;
    #pragma unroll
    for (int g = 0; g < GRP; ++g) {
        double s = 0.0;
        #pragma unroll
        for (int j = 0; j < GRP; ++j) s += exp((double)xrow[g * GRP + j]);
        if (s > best) { best = s; bi = g; }
    }
    return bi;
}

// Validated compute core (R4/R5/R9): one row from LDS -> pred/loss/dist.
__device__ __forceinline__ void do_row(
    const float* __restrict__ xr, const float* __restrict__ xg,
    int t, float* __restrict__ outp, unsigned& lq, unsigned& dT)
{
    float gs[GRP];
    #pragma unroll
    for (int g = 0; g < GRP; ++g) {
        float s = 0.0f;
        #pragma unroll
        for (int j = 0; j < GRP; ++j) s += __expf(xr[g * GRP + j]);
        gs[g] = s;
    }
    float S = gs[0];
    #pragma unroll
    for (int g = 1; g < GRP; ++g) S += gs[g];

    float g1 = gs[0], g2 = -1e30f; int gi = 0;
    #pragma unroll
    for (int g = 1; g < GRP; ++g) {
        const float v = gs[g];
        const bool gt2 = v > g1;
        g2 = gt2 ? g1 : (v > g2 ? v : g2);
        g1 = gt2 ? v  : g1;
        gi = gt2 ? g  : gi;
    }

    const int parent = t / GRP;
    float gpar = gs[0];
    #pragma unroll
    for (int g = 1; g < GRP; ++g)
        gpar = (parent == g) ? gs[g] : gpar;       // static-index select chain

    if (g1 - g2 < 1e-5f * g1) gi = refine_group_f64(xg);

    // within-group argmax on RAW x — exp/softmax monotonic, so EXACT
    const int wb = gi * GRP;
    float w1 = xr[wb]; int wi = 0;
    #pragma unroll
    for (int j = 1; j < GRP; ++j) {
        const float v = xr[wb + j];
        if (v > w1) { w1 = v; wi = j; }
    }
    const int pred = gi * GRP + wi;

    const float et  = expf(xr[t]);                 // precise ocml exp, once/row
    const float win = 0.5f * (gpar + et) / S;
    const float nl  = -logf(win);
    lq += (unsigned)lrintf(nl * FIX);              // nl < ~23 -> fits easily
    dT += (pred == t) ? 0u : ((gi == parent) ? 1u : 2u);

    *outp = (float)pred;
}

__global__ __launch_bounds__(THR) void hl_main(
    const float* __restrict__ x, const int* __restrict__ tgt,
    float* __restrict__ out,
    unsigned* __restrict__ partL, unsigned short* __restrict__ partD)
{
    __shared__ float tile[TILEF];                // 10,368 B -> 15 single-wave blocks/CU
    const int lane = threadIdx.x;
    const int blk  = blockIdx.x;
    const size_t tbase = (size_t)blk * TILEF;
    const float* gt = x + tbase;

    int t = 0;
    if (lane < ROWS) t = tgt[blk * ROWS + lane]; // 1 VMEM (lanes 0-31)

    // issue the whole tile: 10 full ops + tail (lanes<8) = 11 DMA ops
    #pragma unroll
    for (int r = 0; r < FULLR; ++r) {
        const int i = r * THR + lane;
        gload_lds16(gt + 4 * i, &tile[4 * i]);
    }
    if (lane < TAIL) {
        const int i = FULLR * THR + lane;
        gload_lds16(gt + 4 * i, &tile[4 * i]);
    }

    asm volatile("s_waitcnt vmcnt(0)" ::: "memory");
    __builtin_amdgcn_sched_barrier(0);

    unsigned lq = 0, dT = 0;
    if (lane < ROWS) {
        do_row(tile + lane * LCLS, x + tbase + (size_t)lane * LCLS,
               t, out + 1 + blk * ROWS + lane, lq, dT);
    }

    // butterfly over 64 lanes (lanes 32-63 contribute zeros)
    #pragma unroll
    for (int off = 32; off > 0; off >>= 1) {
        lq += __shfl_down(lq, off);
        dT += __shfl_down(dT, off);
    }
    if (lane == 0) {
        partL[blk] = lq;                          // <= 23*2^20*32 ~ 7.7e8, u32-safe
        partD[blk] = (unsigned short)dT;          // <= 64
    }
}

__global__ __launch_bounds__(1024) void hl_final(
    const unsigned* __restrict__ partL, const unsigned short* __restrict__ partD,
    unsigned long long* __restrict__ acc, float* __restrict__ out)
{
    const int idx = blockIdx.x * 1024 + threadIdx.x;
    unsigned long long a = 0, b = 0;
    for (int i = idx; i < NBLK; i += 8 * 1024) { a += partL[i]; b += partD[i]; }
    #pragma unroll
    for (int off = 32; off > 0; off >>= 1) { a += __shfl_down(a, off); b += __shfl_down(b, off); }
    __shared__ unsigned long long rA[16], rB[16];
    const int tid = threadIdx.x;
    if ((tid & 63) == 0) { rA[tid >> 6] = a; rB[tid >> 6] = b; }
    __syncthreads();
    if (tid == 0) {
        unsigned long long ta = 0, tb = 0;
        #pragma unroll
        for (int w = 0; w < 16; ++w) { ta += rA[w]; tb += rB[w]; }
        atomicAdd(&acc[0], ta);
        atomicAdd(&acc[1], tb);
        __threadfence();
        unsigned* tick = (unsigned*)(acc + 2);
        const unsigned old = atomicAdd(tick, 1u);
        if (old == 7u) {                           // 8th (last) block finalizes
            __threadfence();
            const unsigned long long fa = atomicAdd(&acc[0], 0ull);
            const unsigned long long fb = atomicAdd(&acc[1], 0ull);
            out[0] = (float)(((double)fa / 1048576.0) / (double)BTOT);
            out[1 + BTOT] = (float)fb;
        }
    }
}

extern "C" void kernel_launch(void* const* d_in, const int* in_sizes, int n_in,
                              void* d_out, int out_size, void* d_ws, size_t ws_size,
                              hipStream_t stream) {
    const float* outputs = (const float*)d_in[0];
    const int*   target  = (const int*)d_in[1];
    float* out = (float*)d_out;

    // ws layout: u32 partL[32768] | u16 partD[32768] | u64 acc[2] + u32 ticket
    unsigned*       partL = (unsigned*)d_ws;                          // 131,072 B
    unsigned short* partD = (unsigned short*)((char*)d_ws + 131072);  //  65,536 B
    unsigned long long* acc = (unsigned long long*)((char*)d_ws + 196608); // 24 B

    hipMemsetAsync((char*)d_ws + 196608, 0, 24, stream);  // zero acc+ticket per call
    hl_main<<<NBLK, THR, 0, stream>>>(outputs, target, out, partL, partD);
    hl_final<<<8, 1024, 0, stream>>>(partL, partD, acc, out);
}

// Round 11
// 74.832 us; speedup vs baseline: 1.0824x; 1.0824x over previous
//
#include <hip/hip_runtime.h>
#include <cstdint>

constexpr int BTOT = 1048576;
constexpr int LCLS = 81;
constexpr int GRP  = 9;
constexpr int ROWS = 64;                   // rows per block == threads per block (1 wave)
constexpr int THR  = 64;
constexpr int NBLK = BTOT / ROWS;          // 16384
constexpr int TILE4 = ROWS * LCLS / 4;     // 1296 float4 per tile
constexpr int FULLR = TILE4 / THR;         // 20 full staging rounds
constexpr int TAIL  = TILE4 - FULLR * THR; // 16 leftover float4
constexpr float FIX = 67108864.0f;         // 2^26 fixed-point scale for loss

// Async global->LDS, 16B per lane, no VGPR round-trip (m97 pattern:
// lane-consecutive float4s into a linear LDS tile).
__device__ __forceinline__ void gload_lds16(const float* gsrc, float* ldst) {
    __builtin_amdgcn_global_load_lds(
        (const __attribute__((address_space(1))) void*)gsrc,
        (__attribute__((address_space(3))) void*)ldst,
        16, 0, 0);
}

// Rare knife-edge path (~1e-5 of rows): recompute group argmax in f64.
__device__ __attribute__((noinline)) int refine_group_f64(const float* __restrict__ xrow)
{
    double best = -1.0; int bi = 0;
    #pragma unroll
    for (int g = 0; g < GRP; ++g) {
        double s = 0.0;
        #pragma unroll
        for (int j = 0; j < GRP; ++j) s += exp((double)xrow[g * GRP + j]);
        if (s > best) { best = s; bi = g; }
    }
    return bi;
}

__global__ __launch_bounds__(THR) void hl_main(
    const float* __restrict__ x, const int* __restrict__ tgt,
    float* __restrict__ out, unsigned long long* __restrict__ part)
{
    __shared__ float tile[ROWS * LCLS];        // 20,736 B -> 7 single-wave blocks/CU
    const int tid = threadIdx.x;
    const size_t tbase = (size_t)blockIdx.x * (ROWS * LCLS);
    const float* gt = x + tbase;               // 16B-aligned

    // issue tgt FIRST: retires with the same vmcnt(0) as the tile DMAs
    const int row = blockIdx.x * ROWS + tid;
    const int t = tgt[row];

    // ---- stage: issue the whole tile async before waiting (deep burst) ----
    #pragma unroll
    for (int r = 0; r < FULLR; ++r) {
        const int i = r * THR + tid;           // float4 index
        gload_lds16(gt + 4 * i, &tile[4 * i]);
    }
    if (tid < TAIL) {
        const int i = FULLR * THR + tid;
        gload_lds16(gt + 4 * i, &tile[4 * i]);
    }
    asm volatile("s_waitcnt vmcnt(0)" ::: "memory");   // wave-scoped drain, no s_barrier
    __builtin_amdgcn_sched_barrier(0);

    // ---- one row per thread, all reads from LDS ----
    const float* xr = tile + tid * LCLS;       // stride-81: 2-way bank alias = free

    float gs[GRP];
    #pragma unroll
    for (int g = 0; g < GRP; ++g) {
        float s = 0.0f;
        #pragma unroll
        for (int j = 0; j < GRP; ++j) s += __expf(xr[g * GRP + j]);
        gs[g] = s;
    }
    float S = gs[0];
    #pragma unroll
    for (int g = 1; g < GRP; ++g) S += gs[g];

    // group argmax, top-2 tracked (strict >, first index wins)
    float g1 = gs[0], g2 = -1e30f; int gi = 0;
    #pragma unroll
    for (int g = 1; g < GRP; ++g) {
        float v = gs[g];
        bool gt2 = v > g1;
        g2 = gt2 ? g1 : (v > g2 ? v : g2);
        g1 = gt2 ? v  : g1;
        gi = gt2 ? g  : gi;
    }

    const int parent = t / GRP;
    float gpar = gs[0];
    #pragma unroll
    for (int g = 1; g < GRP; ++g)
        gpar = (parent == g) ? gs[g] : gpar;   // static-index select chain

    if (g1 - g2 < 1e-5f * g1) gi = refine_group_f64(xr);

    // within-group argmax on RAW x — exp/softmax are monotonic, so EXACT
    const int wb = gi * GRP;
    float w1 = xr[wb]; int wi = 0;
    #pragma unroll
    for (int j = 1; j < GRP; ++j) {
        float v = xr[wb + j];
        if (v > w1) { w1 = v; wi = j; }
    }

    const int pred = gi * GRP + wi;

    float et  = expf(xr[t]);                   // precise ocml exp, once per row
    float win = 0.5f * (gpar + et) / S;
    float nl  = -logf(win);
    unsigned long long lq = (unsigned long long)llrintf(nl * FIX);
    int dist = (pred == t) ? 0 : ((gi == parent) ? 1 : 2);

    out[1 + row] = (float)pred;

    // ---- deterministic single-wave reduction: fixed-point loss + int dist ----
    #pragma unroll
    for (int off = 32; off > 0; off >>= 1) {
        lq   += __shfl_down(lq, off);
        dist += __shfl_down(dist, off);
    }
    if (tid == 0) {
        part[blockIdx.x] = lq;
        part[NBLK + blockIdx.x] = (unsigned long long)(unsigned)dist;
    }
}

__global__ __launch_bounds__(1024) void hl_final(
    const unsigned long long* __restrict__ part, float* __restrict__ out)
{
    const int tid = threadIdx.x;
    unsigned long long a = 0, b = 0;
    for (int i = tid; i < NBLK; i += 1024) { a += part[i]; b += part[NBLK + i]; }
    #pragma unroll
    for (int off = 32; off > 0; off >>= 1) { a += __shfl_down(a, off); b += __shfl_down(b, off); }
    __shared__ unsigned long long rA[16], rB[16];
    if ((tid & 63) == 0) { rA[tid >> 6] = a; rB[tid >> 6] = b; }
    __syncthreads();
    if (tid == 0) {
        unsigned long long ta = 0, tb = 0;
        #pragma unroll
        for (int w = 0; w < 16; ++w) { ta += rA[w]; tb += rB[w]; }
        double loss = ((double)ta / 67108864.0) / (double)BTOT;
        out[0] = (float)loss;                  // -mean(log(win))
        out[1 + BTOT] = (float)tb;             // total_dist
    }
}

extern "C" void kernel_launch(void* const* d_in, const int* in_sizes, int n_in,
                              void* d_out, int out_size, void* d_ws, size_t ws_size,
                              hipStream_t stream) {
    const float* outputs = (const float*)d_in[0];
    const int*   target  = (const int*)d_in[1];
    float* out = (float*)d_out;
    unsigned long long* part = (unsigned long long*)d_ws;   // needs 2*16384*8 = 262,144 B

    hl_main<<<NBLK, THR, 0, stream>>>(outputs, target, out, part);
    hl_final<<<1, 1024, 0, stream>>>(part, out);
}